// Round 2
// baseline (724.240 us; speedup 1.0000x reference)
//
#include <hip/hip_runtime.h>

#define N_NODES 50000
#define N_ENT   100000
#define N_REL   16
#define DIM     128
#define E_EDGES 600000
#define NQ      8192
#define PATH_DIM 5
#define NK      (N_NODES * N_REL)        /* 800000 (rel,dst) segments, rel-major */
#define NBLK_SEG (NK / 256)              /* 3125 */
#define KTOT    (N_REL * DIM + DIM)      /* 2176 */
#define NG      (KTOT / 32)              /* 68 k-groups of 32 */
#define BM      64                       /* fused-layer block rows */

typedef __attribute__((ext_vector_type(8))) short short8;
typedef __attribute__((ext_vector_type(4))) float floatx4;

static __device__ __forceinline__ short f2bf(float x) {
  unsigned u = __builtin_bit_cast(unsigned, x);
  u = (u + 0x7FFFu + ((u >> 16) & 1u)) >> 16;   // RNE
  return (short)u;
}
static __device__ __forceinline__ float bf_lo(unsigned u) {
  return __builtin_bit_cast(float, u << 16);
}
static __device__ __forceinline__ float bf_hi(unsigned u) {
  return __builtin_bit_cast(float, u & 0xffff0000u);
}
static __device__ __forceinline__ unsigned pk2(float a, float b) {
  return (unsigned)(unsigned short)f2bf(a) | ((unsigned)(unsigned short)f2bf(b) << 16);
}

static __device__ __forceinline__ int wave_incl_scan(int x) {
  int lane = threadIdx.x & 63;
  #pragma unroll
  for (int off = 1; off < 64; off <<= 1) {
    int y = __shfl_up(x, off, 64);
    if (lane >= off) x += y;
  }
  return x;
}

// ---------- edge sort by (etype*N + dst): hist -> scan -> scatter ----------
__global__ void k_hist(const int* __restrict__ ei, const int* __restrict__ et,
                       int* __restrict__ hist) {
  int e = blockIdx.x * 256 + threadIdx.x;
  if (e >= E_EDGES) return;
  int key = et[e] * N_NODES + ei[E_EDGES + e];
  atomicAdd(&hist[key], 1);
}

__global__ void k_bsum(const int* __restrict__ hist, int* __restrict__ bsum) {
  int t = threadIdx.x;
  int v = hist[blockIdx.x * 256 + t];
  #pragma unroll
  for (int off = 32; off; off >>= 1) v += __shfl_xor(v, off, 64);
  __shared__ int s4[4];
  if ((t & 63) == 0) s4[t >> 6] = v;
  __syncthreads();
  if (t == 0) bsum[blockIdx.x] = s4[0] + s4[1] + s4[2] + s4[3];
}

__global__ void k_bscan(int* __restrict__ bsum) {   // 1 block, 1024 threads, 3125 items
  int t = threadIdx.x;
  int v[4], loc[4], s = 0;
  #pragma unroll
  for (int i = 0; i < 4; i++) {
    int idx = t * 4 + i;
    v[i] = (idx < NBLK_SEG) ? bsum[idx] : 0;
    loc[i] = s; s += v[i];
  }
  int incl = wave_incl_scan(s);
  __shared__ int wsum[16];
  int wid = t >> 6, lane = t & 63;
  if (lane == 63) wsum[wid] = incl;
  __syncthreads();
  if (t < 16) {
    int x = wsum[t];
    #pragma unroll
    for (int off = 1; off < 16; off <<= 1) {
      int y = __shfl_up(x, off, 64);
      if (t >= off) x += y;
    }
    wsum[t] = x;
  }
  __syncthreads();
  int wexcl = wid ? wsum[wid - 1] : 0;
  int texcl = wexcl + incl - s;
  #pragma unroll
  for (int i = 0; i < 4; i++) {
    int idx = t * 4 + i;
    if (idx < NBLK_SEG) bsum[idx] = texcl + loc[i];
  }
}

__global__ void k_offsets(const int* __restrict__ hist, const int* __restrict__ bsum,
                          int* __restrict__ offs, int* __restrict__ cursor) {
  int t = threadIdx.x;
  int g = blockIdx.x * 256 + t;
  int v = hist[g];
  int incl = wave_incl_scan(v);
  __shared__ int wsum[4];
  int wid = t >> 6, lane = t & 63;
  if (lane == 63) wsum[wid] = incl;
  __syncthreads();
  int wexcl = 0;
  for (int i = 0; i < wid; i++) wexcl += wsum[i];
  int off = bsum[blockIdx.x] + wexcl + incl - v;
  offs[g] = off;
  cursor[g] = off;
  if (g == NK - 1) offs[NK] = off + v;
}

__global__ void k_scatter(const int* __restrict__ ei, const int* __restrict__ et,
                          int* __restrict__ cursor, int* __restrict__ ssrc) {
  int e = blockIdx.x * 256 + threadIdx.x;
  if (e >= E_EDGES) return;
  int src = ei[e];
  int key = et[e] * N_NODES + ei[E_EDGES + e];
  int pos = atomicAdd(&cursor[key], 1);
  ssrc[pos] = src;
}

// ---------- h0 gather (fp32 emb -> bf16 h) ----------
__global__ void k_h0(const int* __restrict__ nid, const float* __restrict__ emb,
                     unsigned* __restrict__ h) {
  int g = blockIdx.x * 256 + threadIdx.x;     // over N*32
  int n = g >> 5;
  int q = g & 31;
  float4 v = *(const float4*)(emb + (size_t)nid[n] * DIM + q * 4);
  uint2 pk;
  pk.x = pk2(v.x, v.y);
  pk.y = pk2(v.z, v.w);
  *(uint2*)(h + (size_t)n * 64 + q * 2) = pk;
}

// ---------- weights -> bf16 fragment tiles ----------
// layout: [l][g=k/32][nt8=n/16] tile of [16 rA][32 q] shorts (1KB, wave-contiguous)
__global__ void k_wcat(const float* __restrict__ wrel, const float* __restrict__ wself,
                       short* __restrict__ wt) {
  int idx = blockIdx.x * 256 + threadIdx.x;
  if (idx >= 2 * NG * 8 * 512) return;
  int within = idx & 511;
  int tile = idx >> 9;
  int rA = within >> 5, q = within & 31;
  int nt8 = tile & 7;
  int lg = tile >> 3;
  int l = lg / NG, g = lg % NG;
  int n = nt8 * 16 + rA;
  int k = g * 32 + q;
  float v;
  if (k < N_REL * DIM) {
    int r = k >> 7, d = k & 127;
    v = wrel[(((size_t)l * N_REL + r) * DIM + d) * DIM + n];
  } else {
    int d = k - N_REL * DIM;
    v = wself[((size_t)l * DIM + d) * DIM + n];
  }
  wt[idx] = f2bf(v);
}

// ---------- fused layer: per-(dst,rel) mean -> LDS A-tile -> MFMA -> relu ----------
// hout[row] = relu( [mean(dst,r) for r | h_self] @ Wcat^T ), all staged through LDS
__global__ __launch_bounds__(256) void k_layer(const unsigned* __restrict__ hin,
                                               const int* __restrict__ offs,
                                               const int* __restrict__ ssrc,
                                               const short* __restrict__ wt,
                                               unsigned* __restrict__ hout) {
  // 272B row stride: 16B-aligned short8 reads, 8 lanes/bank (minimal) on MFMA reads
  __shared__ unsigned As[BM][68];
  int t = threadIdx.x;
  int w = t >> 6, lane = t & 63;
  int quad = lane >> 4, rA = lane & 15;
  int wm = w >> 1, wn = w & 1;           // wave -> (row-half, col-half)
  int row0 = blockIdx.x * BM;
  floatx4 acc[2][4];
  #pragma unroll
  for (int a = 0; a < 2; a++)
    #pragma unroll
    for (int b = 0; b < 4; b++) acc[a][b] = (floatx4)0.f;

  for (int it = 0; it < 17; ++it) {      // 16 relations + 1 self slot
    __syncthreads();                     // protect As vs previous MFMA readers
    if (it < 16) {
      // wave w owns rows [w*16, w*16+16): 17 contiguous offsets in lanes 0..16
      int keybase = it * N_NODES + row0 + w * 16;
      int o = offs[min(keybase + min(lane, 16), NK)];
      // UNCONDITIONAL shuffle: __shfl is convergent; putting it in a divergent
      // ternary arm reads bpermute slots of EXEC-disabled lanes (undefined).
      // For lane<16 this is identity (source lane == lane), so semantics match.
      int sj = __shfl(o, lane & 15);           // start of segment (lane&15)
      int pa = min(sj + ((lane >> 5) & 1), E_EDGES - 1);
      int pfe = ssrc[pa];                      // lanes 0-31: 1st edge; 32-63: 2nd
      #pragma unroll
      for (int j = 0; j < 16; ++j) {
        int s = __shfl(o, j);
        int e = __shfl(o, j + 1);
        int cnt = e - s;                 // >=0 (offs monotone, clamp monotone)
        float s0 = 0.f, s1 = 0.f;
        if (cnt > 0) {                   // wave-uniform branch (s,e broadcast)
          unsigned u = hin[(size_t)__shfl(pfe, j) * 64 + lane];
          s0 = bf_lo(u); s1 = bf_hi(u);
          if (cnt > 1) {
            unsigned u1 = hin[(size_t)__shfl(pfe, j + 32) * 64 + lane];
            s0 += bf_lo(u1); s1 += bf_hi(u1);
            for (int p = s + 2; p < e; ++p) {         // rare (~4% of segments)
              unsigned u2 = hin[(size_t)ssrc[p] * 64 + lane];
              s0 += bf_lo(u2); s1 += bf_hi(u2);
            }
          }
          float inv = 1.0f / (float)cnt;
          s0 *= inv; s1 *= inv;
        }
        As[w * 16 + j][lane] = pk2(s0, s1);
      }
    } else {
      // self slot: copy h rows directly
      #pragma unroll
      for (int j = 0; j < 16; ++j) {
        int lr = min(row0 + w * 16 + j, N_NODES - 1);
        As[w * 16 + j][lane] = hin[(size_t)lr * 64 + lane];
      }
    }
    __syncthreads();
    const short* arow0 = (const short*)&As[wm * 32 + rA][0];
    const short* arow1 = (const short*)&As[wm * 32 + 16 + rA][0];
    #pragma unroll
    for (int ks = 0; ks < 4; ++ks) {
      short8 a0 = *(const short8*)(arow0 + ks * 32 + quad * 8);
      short8 a1 = *(const short8*)(arow1 + ks * 32 + quad * 8);
      int g = it * 4 + ks;
      const short* bp = wt + (size_t)(g * 8 + wn * 4) * 512 + rA * 32 + quad * 8;
      #pragma unroll
      for (int nt = 0; nt < 4; ++nt) {
        short8 b = *(const short8*)(bp + nt * 512);   // 1KB tile, wave-coalesced, L2-hot
        acc[0][nt] = __builtin_amdgcn_mfma_f32_16x16x32_bf16(a0, b, acc[0][nt], 0, 0, 0);
        acc[1][nt] = __builtin_amdgcn_mfma_f32_16x16x32_bf16(a1, b, acc[1][nt], 0, 0, 0);
      }
    }
  }
  // epilogue: C row=(lane>>4)*4+j, col=lane&15 within each 16x16 tile
  #pragma unroll
  for (int mt = 0; mt < 2; ++mt)
    #pragma unroll
    for (int nt = 0; nt < 4; ++nt)
      #pragma unroll
      for (int j = 0; j < 4; ++j) {
        int row = row0 + wm * 32 + mt * 16 + quad * 4 + j;
        int col = wn * 64 + nt * 16 + rA;
        if (row < N_NODES)
          ((short*)hout)[(size_t)row * DIM + col] = f2bf(fmaxf(acc[mt][nt][j], 0.f));
      }
}

// ---------- scoring (bf16 h) ----------
__global__ void k_score(const unsigned* __restrict__ h, const int* __restrict__ heads,
                        const int* __restrict__ rels, const int* __restrict__ tails,
                        const float* __restrict__ rel_emb, const float* __restrict__ path_feat,
                        const int* __restrict__ task_idx, const float* __restrict__ delta_w,
                        const float* __restrict__ lambda_logit, const float* __restrict__ rule_init,
                        float* __restrict__ out) {
  int q = (blockIdx.x * 256 + threadIdx.x) >> 6;
  int lane = threadIdx.x & 63;
  int hd = heads[q], tl = tails[q], rl = rels[q];
  unsigned ua = h[(size_t)hd * 64 + lane];
  unsigned uc = h[(size_t)tl * 64 + lane];
  float2 r = *(const float2*)(rel_emb + (size_t)rl * DIM + lane * 2);
  float s = bf_lo(ua) * r.x * bf_lo(uc) + bf_hi(ua) * r.y * bf_hi(uc);
  #pragma unroll
  for (int off = 32; off; off >>= 1) s += __shfl_xor(s, off, 64);
  if (lane == 0) {
    int task = task_idx[0];
    float sp = 0.f;
    #pragma unroll
    for (int p = 0; p < PATH_DIM; p++)
      sp += path_feat[q * PATH_DIM + p] *
            (rule_init[task * PATH_DIM + p] + delta_w[task * PATH_DIM + p]);
    float lam = 1.f / (1.f + __expf(-lambda_logit[task]));
    out[q] = lam * s + (1.f - lam) * sp;
  }
}

extern "C" void kernel_launch(void* const* d_in, const int* in_sizes, int n_in,
                              void* d_out, int out_size, void* d_ws, size_t ws_size,
                              hipStream_t stream) {
  const int*   node_ids   = (const int*)d_in[0];
  const int*   edge_index = (const int*)d_in[1];
  const int*   edge_type  = (const int*)d_in[2];
  const int*   heads      = (const int*)d_in[3];
  const int*   rels       = (const int*)d_in[4];
  const int*   tails      = (const int*)d_in[5];
  const float* path_feat  = (const float*)d_in[6];
  const int*   task_idx   = (const int*)d_in[7];
  const float* entity_emb = (const float*)d_in[8];
  const float* rel_emb    = (const float*)d_in[9];
  const float* W_self     = (const float*)d_in[10];
  const float* W_rel      = (const float*)d_in[11];
  const float* delta_w    = (const float*)d_in[12];
  const float* lambda_lg  = (const float*)d_in[13];
  const float* rule_init  = (const float*)d_in[14];

  char* ws = (char*)d_ws;
  size_t off = 0;
  auto alloc = [&](size_t bytes) -> void* {
    void* p = ws + off;
    off = (off + bytes + 255) & ~(size_t)255;
    return p;
  };
  unsigned* h_a    = (unsigned*)alloc((size_t)N_NODES * DIM * 2);
  unsigned* h_b    = (unsigned*)alloc((size_t)N_NODES * DIM * 2);
  short*    wt     = (short*)alloc((size_t)2 * NG * 8 * 512 * 2);
  int*      offs   = (int*)alloc((size_t)(NK + 1) * 4);
  int*      ssrc   = (int*)alloc((size_t)E_EDGES * 4);
  int*      hist   = (int*)alloc((size_t)(NK + 1) * 4);
  int*      cursor = (int*)alloc((size_t)NK * 4);
  int*      bsum   = (int*)alloc((size_t)NBLK_SEG * 4);

  hipMemsetAsync(hist, 0, (size_t)(NK + 1) * 4, stream);
  int eb = (E_EDGES + 255) / 256;
  k_hist<<<eb, 256, 0, stream>>>(edge_index, edge_type, hist);
  k_bsum<<<NBLK_SEG, 256, 0, stream>>>(hist, bsum);
  k_bscan<<<1, 1024, 0, stream>>>(bsum);
  k_offsets<<<NBLK_SEG, 256, 0, stream>>>(hist, bsum, offs, cursor);
  k_scatter<<<eb, 256, 0, stream>>>(edge_index, edge_type, cursor, ssrc);
  k_h0<<<(N_NODES * 32) / 256, 256, 0, stream>>>(node_ids, entity_emb, h_a);
  k_wcat<<<(2 * NG * 8 * 512 + 255) / 256, 256, 0, stream>>>(W_rel, W_self, wt);

  const unsigned* hin = h_a;
  unsigned* hout = h_b;
  int nblk = (N_NODES + BM - 1) / BM;
  for (int l = 0; l < 2; l++) {
    k_layer<<<nblk, 256, 0, stream>>>(hin, offs, ssrc,
                                      wt + (size_t)l * NG * 8 * 512, hout);
    const unsigned* tmp = hout;
    hout = (unsigned*)hin;
    hin = tmp;
  }
  k_score<<<NQ / 4, 256, 0, stream>>>(hin, heads, rels, tails, rel_emb, path_feat,
                                      task_idx, delta_w, lambda_lg, rule_init,
                                      (float*)d_out);
}

// Round 3
// 532.670 us; speedup vs baseline: 1.3596x; 1.3596x over previous
//
#include <hip/hip_runtime.h>

#define N_NODES 50000
#define N_ENT   100000
#define N_REL   16
#define DIM     128
#define E_EDGES 600000
#define NQ      8192
#define PATH_DIM 5
#define NK      (N_NODES * N_REL)        /* 800000 (rel,dst) segments, rel-major */
#define NBLK_SEG (NK / 256)              /* 3125 */
#define KTOT    (N_REL * DIM + DIM)      /* 2176 */
#define NG      (KTOT / 32)              /* 68 k-groups of 32 */
#define BM      64                       /* fused-layer block rows */

typedef __attribute__((ext_vector_type(8))) short short8;
typedef __attribute__((ext_vector_type(4))) float floatx4;

static __device__ __forceinline__ short f2bf(float x) {
  unsigned u = __builtin_bit_cast(unsigned, x);
  u = (u + 0x7FFFu + ((u >> 16) & 1u)) >> 16;   // RNE
  return (short)u;
}
static __device__ __forceinline__ float bf_lo(unsigned u) {
  return __builtin_bit_cast(float, u << 16);
}
static __device__ __forceinline__ float bf_hi(unsigned u) {
  return __builtin_bit_cast(float, u & 0xffff0000u);
}
static __device__ __forceinline__ unsigned pk2(float a, float b) {
  return (unsigned)(unsigned short)f2bf(a) | ((unsigned)(unsigned short)f2bf(b) << 16);
}

static __device__ __forceinline__ int wave_incl_scan(int x) {
  int lane = threadIdx.x & 63;
  #pragma unroll
  for (int off = 1; off < 64; off <<= 1) {
    int y = __shfl_up(x, off, 64);
    if (lane >= off) x += y;
  }
  return x;
}

// ---------- edge sort by (etype*N + dst): hist -> scan -> scatter ----------
__global__ void k_hist(const int* __restrict__ ei, const int* __restrict__ et,
                       int* __restrict__ hist) {
  int e = blockIdx.x * 256 + threadIdx.x;
  if (e >= E_EDGES) return;
  int key = et[e] * N_NODES + ei[E_EDGES + e];
  atomicAdd(&hist[key], 1);
}

__global__ void k_bsum(const int* __restrict__ hist, int* __restrict__ bsum) {
  int t = threadIdx.x;
  int v = hist[blockIdx.x * 256 + t];
  #pragma unroll
  for (int off = 32; off; off >>= 1) v += __shfl_xor(v, off, 64);
  __shared__ int s4[4];
  if ((t & 63) == 0) s4[t >> 6] = v;
  __syncthreads();
  if (t == 0) bsum[blockIdx.x] = s4[0] + s4[1] + s4[2] + s4[3];
}

__global__ void k_bscan(int* __restrict__ bsum) {   // 1 block, 1024 threads, 3125 items
  int t = threadIdx.x;
  int v[4], loc[4], s = 0;
  #pragma unroll
  for (int i = 0; i < 4; i++) {
    int idx = t * 4 + i;
    v[i] = (idx < NBLK_SEG) ? bsum[idx] : 0;
    loc[i] = s; s += v[i];
  }
  int incl = wave_incl_scan(s);
  __shared__ int wsum[16];
  int wid = t >> 6, lane = t & 63;
  if (lane == 63) wsum[wid] = incl;
  __syncthreads();
  if (t < 16) {
    int x = wsum[t];
    #pragma unroll
    for (int off = 1; off < 16; off <<= 1) {
      int y = __shfl_up(x, off, 64);
      if (t >= off) x += y;
    }
    wsum[t] = x;
  }
  __syncthreads();
  int wexcl = wid ? wsum[wid - 1] : 0;
  int texcl = wexcl + incl - s;
  #pragma unroll
  for (int i = 0; i < 4; i++) {
    int idx = t * 4 + i;
    if (idx < NBLK_SEG) bsum[idx] = texcl + loc[i];
  }
}

__global__ void k_offsets(const int* __restrict__ hist, const int* __restrict__ bsum,
                          int* __restrict__ offs, int* __restrict__ cursor) {
  int t = threadIdx.x;
  int g = blockIdx.x * 256 + t;
  int v = hist[g];
  int incl = wave_incl_scan(v);
  __shared__ int wsum[4];
  int wid = t >> 6, lane = t & 63;
  if (lane == 63) wsum[wid] = incl;
  __syncthreads();
  int wexcl = 0;
  for (int i = 0; i < wid; i++) wexcl += wsum[i];
  int off = bsum[blockIdx.x] + wexcl + incl - v;
  offs[g] = off;
  cursor[g] = off;
  if (g == NK - 1) offs[NK] = off + v;
}

__global__ void k_scatter(const int* __restrict__ ei, const int* __restrict__ et,
                          int* __restrict__ cursor, int* __restrict__ ssrc) {
  int e = blockIdx.x * 256 + threadIdx.x;
  if (e >= E_EDGES) return;
  int src = ei[e];
  int key = et[e] * N_NODES + ei[E_EDGES + e];
  int pos = atomicAdd(&cursor[key], 1);
  ssrc[pos] = src;
}

// ---------- h0 gather (fp32 emb -> bf16 h) ----------
__global__ void k_h0(const int* __restrict__ nid, const float* __restrict__ emb,
                     unsigned* __restrict__ h) {
  int g = blockIdx.x * 256 + threadIdx.x;     // over N*32
  int n = g >> 5;
  int q = g & 31;
  float4 v = *(const float4*)(emb + (size_t)nid[n] * DIM + q * 4);
  uint2 pk;
  pk.x = pk2(v.x, v.y);
  pk.y = pk2(v.z, v.w);
  *(uint2*)(h + (size_t)n * 64 + q * 2) = pk;
}

// ---------- weights -> bf16 fragment tiles ----------
// layout: [l][g=k/32][nt8=n/16] tile of [16 rA][32 q] shorts (1KB, wave-contiguous)
__global__ void k_wcat(const float* __restrict__ wrel, const float* __restrict__ wself,
                       short* __restrict__ wt) {
  int idx = blockIdx.x * 256 + threadIdx.x;
  if (idx >= 2 * NG * 8 * 512) return;
  int within = idx & 511;
  int tile = idx >> 9;
  int rA = within >> 5, q = within & 31;
  int nt8 = tile & 7;
  int lg = tile >> 3;
  int l = lg / NG, g = lg % NG;
  int n = nt8 * 16 + rA;
  int k = g * 32 + q;
  float v;
  if (k < N_REL * DIM) {
    int r = k >> 7, d = k & 127;
    v = wrel[(((size_t)l * N_REL + r) * DIM + d) * DIM + n];
  } else {
    int d = k - N_REL * DIM;
    v = wself[((size_t)l * DIM + d) * DIM + n];
  }
  wt[idx] = f2bf(v);
}

// ---------- fused layer: per-(dst,rel) mean -> LDS A-tile -> MFMA -> relu ----------
// Mean phase is fully batched: lanes = (seg 0..15) x (edge 0..3); one ssrc gather
// fetches 4 edge srcs per segment; readlane -> SGPR row -> 64 branchless scalar-base
// row loads in flight. Invalid edges load a zeroed 256B page (L1-hot) so the
// accumulate is an unconditional sum. cnt>4 tail (~0.1% segments) is serial.
__global__ __launch_bounds__(256) void k_layer(const unsigned* __restrict__ hin,
                                               const int* __restrict__ offs,
                                               const int* __restrict__ ssrc,
                                               const short* __restrict__ wt,
                                               const unsigned* __restrict__ zrow,
                                               unsigned* __restrict__ hout) {
  __shared__ unsigned As[BM][68];     // 272B row stride
  __shared__ int offsS[16][66];       // per-rel segment boundaries for block rows
  int t = threadIdx.x;
  int w = t >> 6, lane = t & 63;
  int quad = lane >> 4, rA = lane & 15;
  int wm = w >> 1, wn = w & 1;        // wave -> (row-half, col-half)
  int row0 = blockIdx.x * BM;

  // stage all offsets this block needs: 16 rels x 65 boundaries (coalesced)
  #pragma unroll
  for (int rep = 0; rep < 5; ++rep) {
    int idx = rep * 256 + t;
    if (idx < 16 * 80) {
      int it = idx / 80, r = idx - it * 80;
      if (r < 65) {
        int g = it * N_NODES + row0 + r;
        offsS[it][r] = offs[min(g, NK)];
      }
    }
  }

  floatx4 acc[2][4];
  #pragma unroll
  for (int a = 0; a < 2; a++)
    #pragma unroll
    for (int b = 0; b < 4; b++) acc[a][b] = (floatx4)0.f;

  __syncthreads();

  int seg = lane & 15, edge = lane >> 4;
  // prologue: gather first-4-edge srcs for it=0
  int s_l = offsS[0][w * 16 + seg];
  int e_l = offsS[0][w * 16 + seg + 1];
  int pfe = ssrc[min(s_l + edge, E_EDGES - 1)];

  for (int it = 0; it < 17; ++it) {
    if (it < 16) {
      int cl = e_l - s_l;                 // per-lane cnt of segment (lane&15)
      unsigned u0[16], u1[16], u2[16], u3[16];
      // phase 1: issue all 64 row loads (branchless, scalar base select)
      #pragma unroll
      for (int j = 0; j < 16; ++j) {
        int cnt = __builtin_amdgcn_readlane(cl, j);
        int r0 = __builtin_amdgcn_readlane(pfe, j);
        int r1 = __builtin_amdgcn_readlane(pfe, j + 16);
        int r2 = __builtin_amdgcn_readlane(pfe, j + 32);
        int r3 = __builtin_amdgcn_readlane(pfe, j + 48);
        const unsigned* p0 = (cnt > 0) ? hin + (size_t)r0 * 64 : zrow;
        const unsigned* p1 = (cnt > 1) ? hin + (size_t)r1 * 64 : zrow;
        const unsigned* p2 = (cnt > 2) ? hin + (size_t)r2 * 64 : zrow;
        const unsigned* p3 = (cnt > 3) ? hin + (size_t)r3 * 64 : zrow;
        u0[j] = p0[lane];
        u1[j] = p1[lane];
        u2[j] = p2[lane];
        u3[j] = p3[lane];
      }
      // prefetch next iteration's edge srcs (overlaps with accumulate+MFMA)
      int pfe_n = 0, s_n = 0, e_n = 0;
      if (it < 15) {
        s_n = offsS[it + 1][w * 16 + seg];
        e_n = offsS[it + 1][w * 16 + seg + 1];
        pfe_n = ssrc[min(s_n + edge, E_EDGES - 1)];
      }
      // phase 2: accumulate -> As
      #pragma unroll
      for (int j = 0; j < 16; ++j) {
        int cnt = __builtin_amdgcn_readlane(cl, j);
        float s0 = bf_lo(u0[j]) + bf_lo(u1[j]) + bf_lo(u2[j]) + bf_lo(u3[j]);
        float s1 = bf_hi(u0[j]) + bf_hi(u1[j]) + bf_hi(u2[j]) + bf_hi(u3[j]);
        if (cnt > 4) {                    // uniform branch, ~0.1% of segments
          int sj = __builtin_amdgcn_readlane(s_l, j);
          for (int p = sj + 4; p < sj + cnt; ++p) {
            int sr = __builtin_amdgcn_readfirstlane(ssrc[p]);
            unsigned uu = hin[(size_t)sr * 64 + lane];
            s0 += bf_lo(uu); s1 += bf_hi(uu);
          }
        }
        float inv = 1.0f / (float)(cnt > 0 ? cnt : 1);
        As[w * 16 + j][lane] = pk2(s0 * inv, s1 * inv);
      }
      pfe = pfe_n; s_l = s_n; e_l = e_n;
    } else {
      // self slot: copy h rows directly
      #pragma unroll
      for (int j = 0; j < 16; ++j) {
        int lr = min(row0 + w * 16 + j, N_NODES - 1);
        As[w * 16 + j][lane] = hin[(size_t)lr * 64 + lane];
      }
    }
    __syncthreads();
    const short* arow0 = (const short*)&As[wm * 32 + rA][0];
    const short* arow1 = (const short*)&As[wm * 32 + 16 + rA][0];
    #pragma unroll
    for (int ks = 0; ks < 4; ++ks) {
      short8 a0 = *(const short8*)(arow0 + ks * 32 + quad * 8);
      short8 a1 = *(const short8*)(arow1 + ks * 32 + quad * 8);
      int kg = it * 4 + ks;
      const short* bp = wt + (size_t)(kg * 8 + wn * 4) * 512 + rA * 32 + quad * 8;
      #pragma unroll
      for (int nt = 0; nt < 4; ++nt) {
        short8 b = *(const short8*)(bp + nt * 512);   // 1KB tile, wave-coalesced, L2-hot
        acc[0][nt] = __builtin_amdgcn_mfma_f32_16x16x32_bf16(a0, b, acc[0][nt], 0, 0, 0);
        acc[1][nt] = __builtin_amdgcn_mfma_f32_16x16x32_bf16(a1, b, acc[1][nt], 0, 0, 0);
      }
    }
    __syncthreads();
  }
  // epilogue: C row=(lane>>4)*4+j, col=lane&15 within each 16x16 tile
  #pragma unroll
  for (int mt = 0; mt < 2; ++mt)
    #pragma unroll
    for (int nt = 0; nt < 4; ++nt)
      #pragma unroll
      for (int j = 0; j < 4; ++j) {
        int row = row0 + wm * 32 + mt * 16 + quad * 4 + j;
        int col = wn * 64 + nt * 16 + rA;
        if (row < N_NODES)
          ((short*)hout)[(size_t)row * DIM + col] = f2bf(fmaxf(acc[mt][nt][j], 0.f));
      }
}

// ---------- scoring (bf16 h) ----------
__global__ void k_score(const unsigned* __restrict__ h, const int* __restrict__ heads,
                        const int* __restrict__ rels, const int* __restrict__ tails,
                        const float* __restrict__ rel_emb, const float* __restrict__ path_feat,
                        const int* __restrict__ task_idx, const float* __restrict__ delta_w,
                        const float* __restrict__ lambda_logit, const float* __restrict__ rule_init,
                        float* __restrict__ out) {
  int q = (blockIdx.x * 256 + threadIdx.x) >> 6;
  int lane = threadIdx.x & 63;
  int hd = heads[q], tl = tails[q], rl = rels[q];
  unsigned ua = h[(size_t)hd * 64 + lane];
  unsigned uc = h[(size_t)tl * 64 + lane];
  float2 r = *(const float2*)(rel_emb + (size_t)rl * DIM + lane * 2);
  float s = bf_lo(ua) * r.x * bf_lo(uc) + bf_hi(ua) * r.y * bf_hi(uc);
  #pragma unroll
  for (int off = 32; off; off >>= 1) s += __shfl_xor(s, off, 64);
  if (lane == 0) {
    int task = task_idx[0];
    float sp = 0.f;
    #pragma unroll
    for (int p = 0; p < PATH_DIM; p++)
      sp += path_feat[q * PATH_DIM + p] *
            (rule_init[task * PATH_DIM + p] + delta_w[task * PATH_DIM + p]);
    float lam = 1.f / (1.f + __expf(-lambda_logit[task]));
    out[q] = lam * s + (1.f - lam) * sp;
  }
}

extern "C" void kernel_launch(void* const* d_in, const int* in_sizes, int n_in,
                              void* d_out, int out_size, void* d_ws, size_t ws_size,
                              hipStream_t stream) {
  const int*   node_ids   = (const int*)d_in[0];
  const int*   edge_index = (const int*)d_in[1];
  const int*   edge_type  = (const int*)d_in[2];
  const int*   heads      = (const int*)d_in[3];
  const int*   rels       = (const int*)d_in[4];
  const int*   tails      = (const int*)d_in[5];
  const float* path_feat  = (const float*)d_in[6];
  const int*   task_idx   = (const int*)d_in[7];
  const float* entity_emb = (const float*)d_in[8];
  const float* rel_emb    = (const float*)d_in[9];
  const float* W_self     = (const float*)d_in[10];
  const float* W_rel      = (const float*)d_in[11];
  const float* delta_w    = (const float*)d_in[12];
  const float* lambda_lg  = (const float*)d_in[13];
  const float* rule_init  = (const float*)d_in[14];

  char* ws = (char*)d_ws;
  size_t off = 0;
  auto alloc = [&](size_t bytes) -> void* {
    void* p = ws + off;
    off = (off + bytes + 255) & ~(size_t)255;
    return p;
  };
  unsigned* h_a    = (unsigned*)alloc((size_t)N_NODES * DIM * 2);
  unsigned* h_b    = (unsigned*)alloc((size_t)N_NODES * DIM * 2);
  short*    wt     = (short*)alloc((size_t)2 * NG * 8 * 512 * 2);
  int*      offs   = (int*)alloc((size_t)(NK + 1) * 4);
  int*      ssrc   = (int*)alloc((size_t)E_EDGES * 4);
  int*      hist   = (int*)alloc((size_t)(NK + 1) * 4);
  int*      cursor = (int*)alloc((size_t)NK * 4);
  int*      bsum   = (int*)alloc((size_t)NBLK_SEG * 4);
  unsigned* zrow   = (unsigned*)alloc(256);

  hipMemsetAsync(hist, 0, (size_t)(NK + 1) * 4, stream);
  hipMemsetAsync(zrow, 0, 256, stream);
  int eb = (E_EDGES + 255) / 256;
  k_hist<<<eb, 256, 0, stream>>>(edge_index, edge_type, hist);
  k_bsum<<<NBLK_SEG, 256, 0, stream>>>(hist, bsum);
  k_bscan<<<1, 1024, 0, stream>>>(bsum);
  k_offsets<<<NBLK_SEG, 256, 0, stream>>>(hist, bsum, offs, cursor);
  k_scatter<<<eb, 256, 0, stream>>>(edge_index, edge_type, cursor, ssrc);
  k_h0<<<(N_NODES * 32) / 256, 256, 0, stream>>>(node_ids, entity_emb, h_a);
  k_wcat<<<(2 * NG * 8 * 512 + 255) / 256, 256, 0, stream>>>(W_rel, W_self, wt);

  const unsigned* hin = h_a;
  unsigned* hout = h_b;
  int nblk = (N_NODES + BM - 1) / BM;
  for (int l = 0; l < 2; l++) {
    k_layer<<<nblk, 256, 0, stream>>>(hin, offs, ssrc,
                                      wt + (size_t)l * NG * 8 * 512, zrow, hout);
    const unsigned* tmp = hout;
    hout = (unsigned*)hin;
    hin = tmp;
  }
  k_score<<<NQ / 4, 256, 0, stream>>>(hin, heads, rels, tails, rel_emb, path_feat,
                                      task_idx, delta_w, lambda_lg, rule_init,
                                      (float*)d_out);
}

// Round 4
// 491.082 us; speedup vs baseline: 1.4748x; 1.0847x over previous
//
#include <hip/hip_runtime.h>

#define N_NODES 50000
#define N_ENT   100000
#define N_REL   16
#define DIM     128
#define E_EDGES 600000
#define NQ      8192
#define PATH_DIM 5
#define NK      (N_NODES * N_REL)        /* 800000 (rel,dst) segments, rel-major */
#define NBLK_SEG (NK / 256)              /* 3125 */
#define KTOT    (N_REL * DIM + DIM)      /* 2176 */
#define NG      (KTOT / 32)              /* 68 k-groups of 32 */
#define BM      64                       /* fused-layer block rows */

typedef __attribute__((ext_vector_type(8))) short short8;
typedef __attribute__((ext_vector_type(4))) float floatx4;

static __device__ __forceinline__ short f2bf(float x) {
  unsigned u = __builtin_bit_cast(unsigned, x);
  u = (u + 0x7FFFu + ((u >> 16) & 1u)) >> 16;   // RNE
  return (short)u;
}
static __device__ __forceinline__ float bf_lo(unsigned u) {
  return __builtin_bit_cast(float, u << 16);
}
static __device__ __forceinline__ float bf_hi(unsigned u) {
  return __builtin_bit_cast(float, u & 0xffff0000u);
}
static __device__ __forceinline__ unsigned pk2(float a, float b) {
  return (unsigned)(unsigned short)f2bf(a) | ((unsigned)(unsigned short)f2bf(b) << 16);
}

static __device__ __forceinline__ int wave_incl_scan(int x) {
  int lane = threadIdx.x & 63;
  #pragma unroll
  for (int off = 1; off < 64; off <<= 1) {
    int y = __shfl_up(x, off, 64);
    if (lane >= off) x += y;
  }
  return x;
}

// ---------- edge sort by (etype*N + dst): hist -> scan -> scatter ----------
__global__ void k_hist(const int* __restrict__ ei, const int* __restrict__ et,
                       int* __restrict__ hist) {
  int e = blockIdx.x * 256 + threadIdx.x;
  if (e >= E_EDGES) return;
  int key = et[e] * N_NODES + ei[E_EDGES + e];
  atomicAdd(&hist[key], 1);
}

__global__ void k_bsum(const int* __restrict__ hist, int* __restrict__ bsum) {
  int t = threadIdx.x;
  int v = hist[blockIdx.x * 256 + t];
  #pragma unroll
  for (int off = 32; off; off >>= 1) v += __shfl_xor(v, off, 64);
  __shared__ int s4[4];
  if ((t & 63) == 0) s4[t >> 6] = v;
  __syncthreads();
  if (t == 0) bsum[blockIdx.x] = s4[0] + s4[1] + s4[2] + s4[3];
}

__global__ void k_bscan(int* __restrict__ bsum) {   // 1 block, 1024 threads, 3125 items
  int t = threadIdx.x;
  int v[4], loc[4], s = 0;
  #pragma unroll
  for (int i = 0; i < 4; i++) {
    int idx = t * 4 + i;
    v[i] = (idx < NBLK_SEG) ? bsum[idx] : 0;
    loc[i] = s; s += v[i];
  }
  int incl = wave_incl_scan(s);
  __shared__ int wsum[16];
  int wid = t >> 6, lane = t & 63;
  if (lane == 63) wsum[wid] = incl;
  __syncthreads();
  if (t < 16) {
    int x = wsum[t];
    #pragma unroll
    for (int off = 1; off < 16; off <<= 1) {
      int y = __shfl_up(x, off, 64);
      if (t >= off) x += y;
    }
    wsum[t] = x;
  }
  __syncthreads();
  int wexcl = wid ? wsum[wid - 1] : 0;
  int texcl = wexcl + incl - s;
  #pragma unroll
  for (int i = 0; i < 4; i++) {
    int idx = t * 4 + i;
    if (idx < NBLK_SEG) bsum[idx] = texcl + loc[i];
  }
}

__global__ void k_offsets(const int* __restrict__ hist, const int* __restrict__ bsum,
                          int* __restrict__ offs, int* __restrict__ cursor) {
  int t = threadIdx.x;
  int g = blockIdx.x * 256 + t;
  int v = hist[g];
  int incl = wave_incl_scan(v);
  __shared__ int wsum[4];
  int wid = t >> 6, lane = t & 63;
  if (lane == 63) wsum[wid] = incl;
  __syncthreads();
  int wexcl = 0;
  for (int i = 0; i < wid; i++) wexcl += wsum[i];
  int off = bsum[blockIdx.x] + wexcl + incl - v;
  offs[g] = off;
  cursor[g] = off;
  if (g == NK - 1) offs[NK] = off + v;
}

__global__ void k_scatter(const int* __restrict__ ei, const int* __restrict__ et,
                          int* __restrict__ cursor, int* __restrict__ ssrc) {
  int e = blockIdx.x * 256 + threadIdx.x;
  if (e >= E_EDGES) return;
  int src = ei[e];
  int key = et[e] * N_NODES + ei[E_EDGES + e];
  int pos = atomicAdd(&cursor[key], 1);
  ssrc[pos] = src;
}

// ---------- h0 gather (fp32 emb -> bf16 h) ----------
__global__ void k_h0(const int* __restrict__ nid, const float* __restrict__ emb,
                     unsigned* __restrict__ h) {
  int g = blockIdx.x * 256 + threadIdx.x;     // over N*32
  int n = g >> 5;
  int q = g & 31;
  float4 v = *(const float4*)(emb + (size_t)nid[n] * DIM + q * 4);
  uint2 pk;
  pk.x = pk2(v.x, v.y);
  pk.y = pk2(v.z, v.w);
  *(uint2*)(h + (size_t)n * 64 + q * 2) = pk;
}

// ---------- weights -> bf16 fragment tiles ----------
// layout: [l][g=k/32][nt8=n/16] tile of [16 rA][32 q] shorts (1KB, wave-contiguous)
__global__ void k_wcat(const float* __restrict__ wrel, const float* __restrict__ wself,
                       short* __restrict__ wt) {
  int idx = blockIdx.x * 256 + threadIdx.x;
  if (idx >= 2 * NG * 8 * 512) return;
  int within = idx & 511;
  int tile = idx >> 9;
  int rA = within >> 5, q = within & 31;
  int nt8 = tile & 7;
  int lg = tile >> 3;
  int l = lg / NG, g = lg % NG;
  int n = nt8 * 16 + rA;
  int k = g * 32 + q;
  float v;
  if (k < N_REL * DIM) {
    int r = k >> 7, d = k & 127;
    v = wrel[(((size_t)l * N_REL + r) * DIM + d) * DIM + n];
  } else {
    int d = k - N_REL * DIM;
    v = wself[((size_t)l * DIM + d) * DIM + n];
  }
  wt[idx] = f2bf(v);
}

// ---------- fused layer, producer/consumer wave split ----------
// 8 waves: w0-3 produce per-(dst,rel) means into double-buffered As; w4-7 MFMA.
// Producer register file is free of the accumulator -> all 64 gathers in flight.
// One barrier per iteration; gather of tile it+1 overlaps MFMA of tile it.
__global__ __launch_bounds__(512, 4) void k_layer(const unsigned* __restrict__ hin,
                                                  const int* __restrict__ offs,
                                                  const int* __restrict__ ssrc,
                                                  const short* __restrict__ wt,
                                                  const unsigned* __restrict__ zrow,
                                                  unsigned* __restrict__ hout) {
  __shared__ unsigned As[2][BM][68];  // 272B row stride, double-buffered
  __shared__ int offsS[16][66];       // per-rel segment boundaries for block rows
  int t = threadIdx.x;
  int w = t >> 6, lane = t & 63;
  int row0 = blockIdx.x * BM;

  // stage all offsets this block needs: 16 rels x 65 boundaries (coalesced)
  for (int idx = t; idx < 16 * 80; idx += 512) {
    int it = idx / 80, r = idx - it * 80;
    if (r < 65) offsS[it][r] = offs[min(it * N_NODES + row0 + r, NK)];
  }
  __syncthreads();

  if (w < 4) {
    // ================= producer waves =================
    int pw = w;
    int seg = lane & 15, edge = lane >> 4;
    int s_l = offsS[0][pw * 16 + seg];
    int e_l = offsS[0][pw * 16 + seg + 1];
    int pfe = ssrc[min(s_l + edge, E_EDGES - 1)];

    auto produce = [&](int buf, int it) {
      int cl = e_l - s_l;               // per-lane cnt of segment (lane&15)
      unsigned u0[16], u1[16], u2[16], u3[16];
      // phase 1: issue all 64 row loads (branchless, scalar base select)
      #pragma unroll
      for (int j = 0; j < 16; ++j) {
        int cnt = __builtin_amdgcn_readlane(cl, j);
        int r0 = __builtin_amdgcn_readlane(pfe, j);
        int r1 = __builtin_amdgcn_readlane(pfe, j + 16);
        int r2 = __builtin_amdgcn_readlane(pfe, j + 32);
        int r3 = __builtin_amdgcn_readlane(pfe, j + 48);
        const unsigned* p0 = (cnt > 0) ? hin + (size_t)r0 * 64 : zrow;
        const unsigned* p1 = (cnt > 1) ? hin + (size_t)r1 * 64 : zrow;
        const unsigned* p2 = (cnt > 2) ? hin + (size_t)r2 * 64 : zrow;
        const unsigned* p3 = (cnt > 3) ? hin + (size_t)r3 * 64 : zrow;
        u0[j] = p0[lane];
        u1[j] = p1[lane];
        u2[j] = p2[lane];
        u3[j] = p3[lane];
      }
      // prefetch next relation's boundaries + first-4-edge srcs
      int pfe_n = 0, s_n = 0, e_n = 0;
      if (it < 15) {
        s_n = offsS[it + 1][pw * 16 + seg];
        e_n = offsS[it + 1][pw * 16 + seg + 1];
        pfe_n = ssrc[min(s_n + edge, E_EDGES - 1)];
      }
      // phase 2: accumulate -> As[buf]
      #pragma unroll
      for (int j = 0; j < 16; ++j) {
        int cnt = __builtin_amdgcn_readlane(cl, j);
        float s0 = bf_lo(u0[j]) + bf_lo(u1[j]) + bf_lo(u2[j]) + bf_lo(u3[j]);
        float s1 = bf_hi(u0[j]) + bf_hi(u1[j]) + bf_hi(u2[j]) + bf_hi(u3[j]);
        if (cnt > 4) {                  // uniform branch, ~0.1% of segments
          int sj = __builtin_amdgcn_readlane(s_l, j);
          for (int p = sj + 4; p < sj + cnt; ++p) {
            int sr = __builtin_amdgcn_readfirstlane(ssrc[p]);
            unsigned uu = hin[(size_t)sr * 64 + lane];
            s0 += bf_lo(uu); s1 += bf_hi(uu);
          }
        }
        float inv = 1.0f / (float)(cnt > 0 ? cnt : 1);
        As[buf][pw * 16 + j][lane] = pk2(s0 * inv, s1 * inv);
      }
      s_l = s_n; e_l = e_n; pfe = pfe_n;
    };

    produce(0, 0);                      // fill buf0 for iteration 0
    __syncthreads();
    for (int it = 0; it < 17; ++it) {
      int nx = it + 1;
      if (nx < 16) {
        produce(nx & 1, nx);
      } else if (nx == 16) {            // self slot into buf (16&1)=0
        #pragma unroll
        for (int j = 0; j < 16; ++j) {
          int lr = min(row0 + pw * 16 + j, N_NODES - 1);
          As[0][pw * 16 + j][lane] = hin[(size_t)lr * 64 + lane];
        }
      }
      __syncthreads();
    }
  } else {
    // ================= consumer waves =================
    int wid = w - 4, wm = wid >> 1, wn = wid & 1;   // (row-half, col-half)
    int quad = lane >> 4, rA = lane & 15;
    floatx4 acc[2][4];
    #pragma unroll
    for (int a = 0; a < 2; a++)
      #pragma unroll
      for (int b = 0; b < 4; b++) acc[a][b] = (floatx4)0.f;

    __syncthreads();
    for (int it = 0; it < 17; ++it) {
      int buf = it & 1;
      const short* arow0 = (const short*)&As[buf][wm * 32 + rA][0];
      const short* arow1 = (const short*)&As[buf][wm * 32 + 16 + rA][0];
      #pragma unroll
      for (int ks = 0; ks < 4; ++ks) {
        short8 a0 = *(const short8*)(arow0 + ks * 32 + quad * 8);
        short8 a1 = *(const short8*)(arow1 + ks * 32 + quad * 8);
        int kg = it * 4 + ks;
        const short* bp = wt + (size_t)(kg * 8 + wn * 4) * 512 + rA * 32 + quad * 8;
        #pragma unroll
        for (int nt = 0; nt < 4; ++nt) {
          short8 b = *(const short8*)(bp + nt * 512);  // 1KB tile, L2-hot
          acc[0][nt] = __builtin_amdgcn_mfma_f32_16x16x32_bf16(a0, b, acc[0][nt], 0, 0, 0);
          acc[1][nt] = __builtin_amdgcn_mfma_f32_16x16x32_bf16(a1, b, acc[1][nt], 0, 0, 0);
        }
      }
      __syncthreads();
    }
    // epilogue: C row=(lane>>4)*4+j, col=lane&15 within each 16x16 tile
    #pragma unroll
    for (int mt = 0; mt < 2; ++mt)
      #pragma unroll
      for (int nt = 0; nt < 4; ++nt)
        #pragma unroll
        for (int j = 0; j < 4; ++j) {
          int row = row0 + wm * 32 + mt * 16 + quad * 4 + j;
          int col = wn * 64 + nt * 16 + rA;
          if (row < N_NODES)
            ((short*)hout)[(size_t)row * DIM + col] = f2bf(fmaxf(acc[mt][nt][j], 0.f));
        }
  }
}

// ---------- scoring (bf16 h) ----------
__global__ void k_score(const unsigned* __restrict__ h, const int* __restrict__ heads,
                        const int* __restrict__ rels, const int* __restrict__ tails,
                        const float* __restrict__ rel_emb, const float* __restrict__ path_feat,
                        const int* __restrict__ task_idx, const float* __restrict__ delta_w,
                        const float* __restrict__ lambda_logit, const float* __restrict__ rule_init,
                        float* __restrict__ out) {
  int q = (blockIdx.x * 256 + threadIdx.x) >> 6;
  int lane = threadIdx.x & 63;
  int hd = heads[q], tl = tails[q], rl = rels[q];
  unsigned ua = h[(size_t)hd * 64 + lane];
  unsigned uc = h[(size_t)tl * 64 + lane];
  float2 r = *(const float2*)(rel_emb + (size_t)rl * DIM + lane * 2);
  float s = bf_lo(ua) * r.x * bf_lo(uc) + bf_hi(ua) * r.y * bf_hi(uc);
  #pragma unroll
  for (int off = 32; off; off >>= 1) s += __shfl_xor(s, off, 64);
  if (lane == 0) {
    int task = task_idx[0];
    float sp = 0.f;
    #pragma unroll
    for (int p = 0; p < PATH_DIM; p++)
      sp += path_feat[q * PATH_DIM + p] *
            (rule_init[task * PATH_DIM + p] + delta_w[task * PATH_DIM + p]);
    float lam = 1.f / (1.f + __expf(-lambda_logit[task]));
    out[q] = lam * s + (1.f - lam) * sp;
  }
}

extern "C" void kernel_launch(void* const* d_in, const int* in_sizes, int n_in,
                              void* d_out, int out_size, void* d_ws, size_t ws_size,
                              hipStream_t stream) {
  const int*   node_ids   = (const int*)d_in[0];
  const int*   edge_index = (const int*)d_in[1];
  const int*   edge_type  = (const int*)d_in[2];
  const int*   heads      = (const int*)d_in[3];
  const int*   rels       = (const int*)d_in[4];
  const int*   tails      = (const int*)d_in[5];
  const float* path_feat  = (const float*)d_in[6];
  const int*   task_idx   = (const int*)d_in[7];
  const float* entity_emb = (const float*)d_in[8];
  const float* rel_emb    = (const float*)d_in[9];
  const float* W_self     = (const float*)d_in[10];
  const float* W_rel      = (const float*)d_in[11];
  const float* delta_w    = (const float*)d_in[12];
  const float* lambda_lg  = (const float*)d_in[13];
  const float* rule_init  = (const float*)d_in[14];

  char* ws = (char*)d_ws;
  size_t off = 0;
  auto alloc = [&](size_t bytes) -> void* {
    void* p = ws + off;
    off = (off + bytes + 255) & ~(size_t)255;
    return p;
  };
  unsigned* h_a    = (unsigned*)alloc((size_t)N_NODES * DIM * 2);
  unsigned* h_b    = (unsigned*)alloc((size_t)N_NODES * DIM * 2);
  short*    wt     = (short*)alloc((size_t)2 * NG * 8 * 512 * 2);
  int*      offs   = (int*)alloc((size_t)(NK + 1) * 4);
  int*      ssrc   = (int*)alloc((size_t)E_EDGES * 4);
  int*      hist   = (int*)alloc((size_t)(NK + 1) * 4);
  int*      cursor = (int*)alloc((size_t)NK * 4);
  int*      bsum   = (int*)alloc((size_t)NBLK_SEG * 4);
  unsigned* zrow   = (unsigned*)alloc(256);

  hipMemsetAsync(hist, 0, (size_t)(NK + 1) * 4, stream);
  hipMemsetAsync(zrow, 0, 256, stream);
  int eb = (E_EDGES + 255) / 256;
  k_hist<<<eb, 256, 0, stream>>>(edge_index, edge_type, hist);
  k_bsum<<<NBLK_SEG, 256, 0, stream>>>(hist, bsum);
  k_bscan<<<1, 1024, 0, stream>>>(bsum);
  k_offsets<<<NBLK_SEG, 256, 0, stream>>>(hist, bsum, offs, cursor);
  k_scatter<<<eb, 256, 0, stream>>>(edge_index, edge_type, cursor, ssrc);
  k_h0<<<(N_NODES * 32) / 256, 256, 0, stream>>>(node_ids, entity_emb, h_a);
  k_wcat<<<(2 * NG * 8 * 512 + 255) / 256, 256, 0, stream>>>(W_rel, W_self, wt);

  const unsigned* hin = h_a;
  unsigned* hout = h_b;
  int nblk = (N_NODES + BM - 1) / BM;
  for (int l = 0; l < 2; l++) {
    k_layer<<<nblk, 512, 0, stream>>>(hin, offs, ssrc,
                                      wt + (size_t)l * NG * 8 * 512, zrow, hout);
    const unsigned* tmp = hout;
    hout = (unsigned*)hin;
    hin = tmp;
  }
  k_score<<<NQ / 4, 256, 0, stream>>>(hin, heads, rels, tails, rel_emb, path_feat,
                                      task_idx, delta_w, lambda_lg, rule_init,
                                      (float*)d_out);
}

// Round 5
// 449.280 us; speedup vs baseline: 1.6120x; 1.0930x over previous
//
#include <hip/hip_runtime.h>

#define N_NODES 50000
#define N_ENT   100000
#define N_REL   16
#define DIM     128
#define E_EDGES 600000
#define NQ      8192
#define PATH_DIM 5
#define NK      (N_NODES * N_REL)        /* 800000 (rel,dst) segments, rel-major */
#define NBLK_SEG (NK / 256)              /* 3125 */
#define KTOT    (N_REL * DIM + DIM)      /* 2176 */
#define NG      (KTOT / 32)              /* 68 k-groups of 32 */
#define BM      64                       /* fused-layer block rows */

typedef __attribute__((ext_vector_type(8))) short short8;
typedef __attribute__((ext_vector_type(4))) float floatx4;

static __device__ __forceinline__ short f2bf(float x) {
  unsigned u = __builtin_bit_cast(unsigned, x);
  u = (u + 0x7FFFu + ((u >> 16) & 1u)) >> 16;   // RNE
  return (short)u;
}
static __device__ __forceinline__ float bf_lo(unsigned u) {
  return __builtin_bit_cast(float, u << 16);
}
static __device__ __forceinline__ float bf_hi(unsigned u) {
  return __builtin_bit_cast(float, u & 0xffff0000u);
}
static __device__ __forceinline__ unsigned pk2(float a, float b) {
  return (unsigned)(unsigned short)f2bf(a) | ((unsigned)(unsigned short)f2bf(b) << 16);
}

static __device__ __forceinline__ int wave_incl_scan(int x) {
  int lane = threadIdx.x & 63;
  #pragma unroll
  for (int off = 1; off < 64; off <<= 1) {
    int y = __shfl_up(x, off, 64);
    if (lane >= off) x += y;
  }
  return x;
}

// ---------- edge sort by (etype*N + dst): hist -> scan -> scatter ----------
__global__ void k_hist(const int* __restrict__ ei, const int* __restrict__ et,
                       int* __restrict__ hist) {
  int e = blockIdx.x * 256 + threadIdx.x;
  if (e >= E_EDGES) return;
  int key = et[e] * N_NODES + ei[E_EDGES + e];
  atomicAdd(&hist[key], 1);
}

__global__ void k_bsum(const int* __restrict__ hist, int* __restrict__ bsum) {
  int t = threadIdx.x;
  int v = hist[blockIdx.x * 256 + t];
  #pragma unroll
  for (int off = 32; off; off >>= 1) v += __shfl_xor(v, off, 64);
  __shared__ int s4[4];
  if ((t & 63) == 0) s4[t >> 6] = v;
  __syncthreads();
  if (t == 0) bsum[blockIdx.x] = s4[0] + s4[1] + s4[2] + s4[3];
}

__global__ void k_bscan(int* __restrict__ bsum) {   // 1 block, 1024 threads, 3125 items
  int t = threadIdx.x;
  int v[4], loc[4], s = 0;
  #pragma unroll
  for (int i = 0; i < 4; i++) {
    int idx = t * 4 + i;
    v[i] = (idx < NBLK_SEG) ? bsum[idx] : 0;
    loc[i] = s; s += v[i];
  }
  int incl = wave_incl_scan(s);
  __shared__ int wsum[16];
  int wid = t >> 6, lane = t & 63;
  if (lane == 63) wsum[wid] = incl;
  __syncthreads();
  if (t < 16) {
    int x = wsum[t];
    #pragma unroll
    for (int off = 1; off < 16; off <<= 1) {
      int y = __shfl_up(x, off, 64);
      if (t >= off) x += y;
    }
    wsum[t] = x;
  }
  __syncthreads();
  int wexcl = wid ? wsum[wid - 1] : 0;
  int texcl = wexcl + incl - s;
  #pragma unroll
  for (int i = 0; i < 4; i++) {
    int idx = t * 4 + i;
    if (idx < NBLK_SEG) bsum[idx] = texcl + loc[i];
  }
}

__global__ void k_offsets(const int* __restrict__ hist, const int* __restrict__ bsum,
                          int* __restrict__ offs, int* __restrict__ cursor) {
  int t = threadIdx.x;
  int g = blockIdx.x * 256 + t;
  int v = hist[g];
  int incl = wave_incl_scan(v);
  __shared__ int wsum[4];
  int wid = t >> 6, lane = t & 63;
  if (lane == 63) wsum[wid] = incl;
  __syncthreads();
  int wexcl = 0;
  for (int i = 0; i < wid; i++) wexcl += wsum[i];
  int off = bsum[blockIdx.x] + wexcl + incl - v;
  offs[g] = off;
  cursor[g] = off;
  if (g == NK - 1) offs[NK] = off + v;
}

__global__ void k_scatter(const int* __restrict__ ei, const int* __restrict__ et,
                          int* __restrict__ cursor, int* __restrict__ ssrc) {
  int e = blockIdx.x * 256 + threadIdx.x;
  if (e >= E_EDGES) return;
  int src = ei[e];
  int key = et[e] * N_NODES + ei[E_EDGES + e];
  int pos = atomicAdd(&cursor[key], 1);
  ssrc[pos] = src;
}

// ---------- h0 gather (fp32 emb -> bf16 h) ----------
__global__ void k_h0(const int* __restrict__ nid, const float* __restrict__ emb,
                     unsigned* __restrict__ h) {
  int g = blockIdx.x * 256 + threadIdx.x;     // over N*32
  int n = g >> 5;
  int q = g & 31;
  float4 v = *(const float4*)(emb + (size_t)nid[n] * DIM + q * 4);
  uint2 pk;
  pk.x = pk2(v.x, v.y);
  pk.y = pk2(v.z, v.w);
  *(uint2*)(h + (size_t)n * 64 + q * 2) = pk;
}

// ---------- weights -> bf16 fragment tiles ----------
// layout: [l][g=k/32][nt8=n/16] tile of [16 rA][32 q] shorts (1KB, wave-contiguous)
__global__ void k_wcat(const float* __restrict__ wrel, const float* __restrict__ wself,
                       short* __restrict__ wt) {
  int idx = blockIdx.x * 256 + threadIdx.x;
  if (idx >= 2 * NG * 8 * 512) return;
  int within = idx & 511;
  int tile = idx >> 9;
  int rA = within >> 5, q = within & 31;
  int nt8 = tile & 7;
  int lg = tile >> 3;
  int l = lg / NG, g = lg % NG;
  int n = nt8 * 16 + rA;
  int k = g * 32 + q;
  float v;
  if (k < N_REL * DIM) {
    int r = k >> 7, d = k & 127;
    v = wrel[(((size_t)l * N_REL + r) * DIM + d) * DIM + n];
  } else {
    int d = k - N_REL * DIM;
    v = wself[((size_t)l * DIM + d) * DIM + n];
  }
  wt[idx] = f2bf(v);
}

// ---------- fused layer, producer/consumer wave split ----------
// 8 waves: w0-3 produce per-(dst,rel) means into double-buffered As; w4-7 MFMA.
// sched_barrier(0) pins all 64 gathers (+prefetch) BEFORE the accumulate so the
// scheduler cannot sink them (round-4 showed VGPR=64 => loads were serialized).
__global__ __launch_bounds__(512, 4) void k_layer(const unsigned* __restrict__ hin,
                                                  const int* __restrict__ offs,
                                                  const int* __restrict__ ssrc,
                                                  const short* __restrict__ wt,
                                                  const unsigned* __restrict__ zrow,
                                                  unsigned* __restrict__ hout) {
  __shared__ unsigned As[2][BM][68];  // 272B row stride, double-buffered
  __shared__ int offsS[16][66];       // per-rel segment boundaries for block rows
  int t = threadIdx.x;
  int w = t >> 6, lane = t & 63;
  int row0 = blockIdx.x * BM;

  // stage all offsets this block needs: 16 rels x 65 boundaries (coalesced)
  for (int idx = t; idx < 16 * 80; idx += 512) {
    int it = idx / 80, r = idx - it * 80;
    if (r < 65) offsS[it][r] = offs[min(it * N_NODES + row0 + r, NK)];
  }
  __syncthreads();

  if (w < 4) {
    // ================= producer waves =================
    int pw = w;
    int seg = lane & 15, edge = lane >> 4;
    int s_l = offsS[0][pw * 16 + seg];
    int e_l = offsS[0][pw * 16 + seg + 1];
    int pfe = ssrc[min(s_l + edge, E_EDGES - 1)];

    auto produce = [&](int buf, int it) {
      int cl = e_l - s_l;               // per-lane cnt (same for all 4 edge groups)
      // one rcp per iteration; distributed below via readlane
      float invl = 1.0f / (float)(cl > 0 ? cl : 1);
      int invb = __builtin_bit_cast(int, invl);
      unsigned u0[16], u1[16], u2[16], u3[16];
      // phase 1: issue all 64 row loads (branchless, scalar base select)
      #pragma unroll
      for (int j = 0; j < 16; ++j) {
        int cnt = __builtin_amdgcn_readlane(cl, j);
        int r0 = __builtin_amdgcn_readlane(pfe, j);
        int r1 = __builtin_amdgcn_readlane(pfe, j + 16);
        int r2 = __builtin_amdgcn_readlane(pfe, j + 32);
        int r3 = __builtin_amdgcn_readlane(pfe, j + 48);
        const unsigned* p0 = (cnt > 0) ? hin + (size_t)r0 * 64 : zrow;
        const unsigned* p1 = (cnt > 1) ? hin + (size_t)r1 * 64 : zrow;
        const unsigned* p2 = (cnt > 2) ? hin + (size_t)r2 * 64 : zrow;
        const unsigned* p3 = (cnt > 3) ? hin + (size_t)r3 * 64 : zrow;
        u0[j] = p0[lane];
        u1[j] = p1[lane];
        u2[j] = p2[lane];
        u3[j] = p3[lane];
      }
      // prefetch next relation's boundaries + first-4-edge srcs
      int pfe_n = 0, s_n = 0, e_n = 0;
      if (it < 15) {
        s_n = offsS[it + 1][pw * 16 + seg];
        e_n = offsS[it + 1][pw * 16 + seg + 1];
        pfe_n = ssrc[min(s_n + edge, E_EDGES - 1)];
      }
      // fence: nothing below may be hoisted above; all 65 loads stay in flight
      __builtin_amdgcn_sched_barrier(0);
      // phase 2: accumulate -> As[buf]
      #pragma unroll
      for (int j = 0; j < 16; ++j) {
        int cnt = __builtin_amdgcn_readlane(cl, j);
        float inv = __builtin_bit_cast(float, __builtin_amdgcn_readlane(invb, j));
        float s0 = bf_lo(u0[j]) + bf_lo(u1[j]) + bf_lo(u2[j]) + bf_lo(u3[j]);
        float s1 = bf_hi(u0[j]) + bf_hi(u1[j]) + bf_hi(u2[j]) + bf_hi(u3[j]);
        if (cnt > 4) {                  // uniform branch, ~0.1% of segments
          int sj = __builtin_amdgcn_readlane(s_l, j);
          for (int p = sj + 4; p < sj + cnt; ++p) {
            int sr = __builtin_amdgcn_readfirstlane(ssrc[p]);
            unsigned uu = hin[(size_t)sr * 64 + lane];
            s0 += bf_lo(uu); s1 += bf_hi(uu);
          }
        }
        s0 *= inv; s1 *= inv;
        unsigned pk;
        asm("v_cvt_pk_bf16_f32 %0, %1, %2" : "=v"(pk) : "v"(s0), "v"(s1));  // RNE
        As[buf][pw * 16 + j][lane] = pk;
      }
      s_l = s_n; e_l = e_n; pfe = pfe_n;
    };

    produce(0, 0);                      // fill buf0 for iteration 0
    __syncthreads();
    for (int it = 0; it < 17; ++it) {
      int nx = it + 1;
      if (nx < 16) {
        produce(nx & 1, nx);
      } else if (nx == 16) {            // self slot into buf (16&1)=0
        #pragma unroll
        for (int j = 0; j < 16; ++j) {
          int lr = min(row0 + pw * 16 + j, N_NODES - 1);
          As[0][pw * 16 + j][lane] = hin[(size_t)lr * 64 + lane];
        }
      }
      __syncthreads();
    }
  } else {
    // ================= consumer waves =================
    int wid = w - 4, wm = wid >> 1, wn = wid & 1;   // (row-half, col-half)
    int quad = lane >> 4, rA = lane & 15;
    floatx4 acc[2][4];
    #pragma unroll
    for (int a = 0; a < 2; a++)
      #pragma unroll
      for (int b = 0; b < 4; b++) acc[a][b] = (floatx4)0.f;

    __syncthreads();
    for (int it = 0; it < 17; ++it) {
      int buf = it & 1;
      const short* arow0 = (const short*)&As[buf][wm * 32 + rA][0];
      const short* arow1 = (const short*)&As[buf][wm * 32 + 16 + rA][0];
      #pragma unroll
      for (int ks = 0; ks < 4; ++ks) {
        short8 a0 = *(const short8*)(arow0 + ks * 32 + quad * 8);
        short8 a1 = *(const short8*)(arow1 + ks * 32 + quad * 8);
        int kg = it * 4 + ks;
        const short* bp = wt + (size_t)(kg * 8 + wn * 4) * 512 + rA * 32 + quad * 8;
        #pragma unroll
        for (int nt = 0; nt < 4; ++nt) {
          short8 b = *(const short8*)(bp + nt * 512);  // 1KB tile, L2-hot
          acc[0][nt] = __builtin_amdgcn_mfma_f32_16x16x32_bf16(a0, b, acc[0][nt], 0, 0, 0);
          acc[1][nt] = __builtin_amdgcn_mfma_f32_16x16x32_bf16(a1, b, acc[1][nt], 0, 0, 0);
        }
      }
      __syncthreads();
    }
    // epilogue: C row=(lane>>4)*4+j, col=lane&15 within each 16x16 tile
    #pragma unroll
    for (int mt = 0; mt < 2; ++mt)
      #pragma unroll
      for (int nt = 0; nt < 4; ++nt)
        #pragma unroll
        for (int j = 0; j < 4; ++j) {
          int row = row0 + wm * 32 + mt * 16 + quad * 4 + j;
          int col = wn * 64 + nt * 16 + rA;
          if (row < N_NODES)
            ((short*)hout)[(size_t)row * DIM + col] = f2bf(fmaxf(acc[mt][nt][j], 0.f));
        }
  }
}

// ---------- scoring (bf16 h) ----------
__global__ void k_score(const unsigned* __restrict__ h, const int* __restrict__ heads,
                        const int* __restrict__ rels, const int* __restrict__ tails,
                        const float* __restrict__ rel_emb, const float* __restrict__ path_feat,
                        const int* __restrict__ task_idx, const float* __restrict__ delta_w,
                        const float* __restrict__ lambda_logit, const float* __restrict__ rule_init,
                        float* __restrict__ out) {
  int q = (blockIdx.x * 256 + threadIdx.x) >> 6;
  int lane = threadIdx.x & 63;
  int hd = heads[q], tl = tails[q], rl = rels[q];
  unsigned ua = h[(size_t)hd * 64 + lane];
  unsigned uc = h[(size_t)tl * 64 + lane];
  float2 r = *(const float2*)(rel_emb + (size_t)rl * DIM + lane * 2);
  float s = bf_lo(ua) * r.x * bf_lo(uc) + bf_hi(ua) * r.y * bf_hi(uc);
  #pragma unroll
  for (int off = 32; off; off >>= 1) s += __shfl_xor(s, off, 64);
  if (lane == 0) {
    int task = task_idx[0];
    float sp = 0.f;
    #pragma unroll
    for (int p = 0; p < PATH_DIM; p++)
      sp += path_feat[q * PATH_DIM + p] *
            (rule_init[task * PATH_DIM + p] + delta_w[task * PATH_DIM + p]);
    float lam = 1.f / (1.f + __expf(-lambda_logit[task]));
    out[q] = lam * s + (1.f - lam) * sp;
  }
}

extern "C" void kernel_launch(void* const* d_in, const int* in_sizes, int n_in,
                              void* d_out, int out_size, void* d_ws, size_t ws_size,
                              hipStream_t stream) {
  const int*   node_ids   = (const int*)d_in[0];
  const int*   edge_index = (const int*)d_in[1];
  const int*   edge_type  = (const int*)d_in[2];
  const int*   heads      = (const int*)d_in[3];
  const int*   rels       = (const int*)d_in[4];
  const int*   tails      = (const int*)d_in[5];
  const float* path_feat  = (const float*)d_in[6];
  const int*   task_idx   = (const int*)d_in[7];
  const float* entity_emb = (const float*)d_in[8];
  const float* rel_emb    = (const float*)d_in[9];
  const float* W_self     = (const float*)d_in[10];
  const float* W_rel      = (const float*)d_in[11];
  const float* delta_w    = (const float*)d_in[12];
  const float* lambda_lg  = (const float*)d_in[13];
  const float* rule_init  = (const float*)d_in[14];

  char* ws = (char*)d_ws;
  size_t off = 0;
  auto alloc = [&](size_t bytes) -> void* {
    void* p = ws + off;
    off = (off + bytes + 255) & ~(size_t)255;
    return p;
  };
  unsigned* h_a    = (unsigned*)alloc((size_t)N_NODES * DIM * 2);
  unsigned* h_b    = (unsigned*)alloc((size_t)N_NODES * DIM * 2);
  short*    wt     = (short*)alloc((size_t)2 * NG * 8 * 512 * 2);
  int*      offs   = (int*)alloc((size_t)(NK + 1) * 4);
  int*      ssrc   = (int*)alloc((size_t)E_EDGES * 4);
  int*      hist   = (int*)alloc((size_t)(NK + 1) * 4);
  int*      cursor = (int*)alloc((size_t)NK * 4);
  int*      bsum   = (int*)alloc((size_t)NBLK_SEG * 4);
  unsigned* zrow   = (unsigned*)alloc(256);

  hipMemsetAsync(hist, 0, (size_t)(NK + 1) * 4, stream);
  hipMemsetAsync(zrow, 0, 256, stream);
  int eb = (E_EDGES + 255) / 256;
  k_hist<<<eb, 256, 0, stream>>>(edge_index, edge_type, hist);
  k_bsum<<<NBLK_SEG, 256, 0, stream>>>(hist, bsum);
  k_bscan<<<1, 1024, 0, stream>>>(bsum);
  k_offsets<<<NBLK_SEG, 256, 0, stream>>>(hist, bsum, offs, cursor);
  k_scatter<<<eb, 256, 0, stream>>>(edge_index, edge_type, cursor, ssrc);
  k_h0<<<(N_NODES * 32) / 256, 256, 0, stream>>>(node_ids, entity_emb, h_a);
  k_wcat<<<(2 * NG * 8 * 512 + 255) / 256, 256, 0, stream>>>(W_rel, W_self, wt);

  const unsigned* hin = h_a;
  unsigned* hout = h_b;
  int nblk = (N_NODES + BM - 1) / BM;
  for (int l = 0; l < 2; l++) {
    k_layer<<<nblk, 512, 0, stream>>>(hin, offs, ssrc,
                                      wt + (size_t)l * NG * 8 * 512, zrow, hout);
    const unsigned* tmp = hout;
    hout = (unsigned*)hin;
    hin = tmp;
  }
  k_score<<<NQ / 4, 256, 0, stream>>>(hin, heads, rels, tails, rel_emb, path_feat,
                                      task_idx, delta_w, lambda_lg, rule_init,
                                      (float*)d_out);
}